// Round 7
// baseline (458.207 us; speedup 1.0000x reference)
//
#include <hip/hip_runtime.h>

// GaborAutoencoder on MI355X (gfx950)
// split fp32 -> fp16 (hi, lo*4096) -> 3-pass split-precision MFMA GEMMs -> Gabor synth.
// R12: G1 rebuilt as counted-vmcnt TRIPLE-buffer pipeline (T4, depth-2 prefetch),
//      with STATIC buffer indices (K-loop tiled x3, macro with literal BUF 0/1/2)
//      -- fixes R6's failure (runtime-indexed bufs -> VALU 40%, VGPR 152).
//      8 waves (512 thr, 2x4 grid, 64x64 wave tiles, acc=128 VGPR) -> 2 waves/SIMD
//      TLP + vmcnt(6) never-drain: LDS unit and MFMA pipe overlap instead of
//      alternating (R8 accounting: both ~40%, wall 2300cy vs 1880 resource bound).
//      LDS 3x48KB = 144KB. One s_barrier per K32 step. R4-verified swizzles kept.
//      G2-4 / splits / combine1 / synth: R11-exact (banked 395.5us).

#define SIGNAL_LEN 2048
#define NWAV 32

typedef _Float16 f16x8 __attribute__((ext_vector_type(8)));
typedef _Float16 f16x4 __attribute__((ext_vector_type(4)));
typedef float    f32x4 __attribute__((ext_vector_type(4)));

__device__ __forceinline__ void load16_lds(const _Float16* g, _Float16* l) {
  __builtin_amdgcn_global_load_lds((const __attribute__((address_space(1))) void*)g,
                                   (__attribute__((address_space(3))) void*)l,
                                   16, 0, 0);
}

struct HL { _Float16 h, l; };
__device__ __forceinline__ HL split_one(float a) {
  HL r;
  r.h = (_Float16)a;
  r.l = (_Float16)((a - (float)r.h) * 4096.0f);
  return r;
}

// ---------------------------------------------------------------------------
// X split: fp32 float4 -> hi/lo f16x4
// ---------------------------------------------------------------------------
__global__ void split_x(const float4* __restrict__ src, f16x4* __restrict__ dh,
                        f16x4* __restrict__ dl) {
  int i = blockIdx.x * 256 + threadIdx.x;  // 4194304 float4s
  float4 v = src[i];
  float a[4] = {v.x, v.y, v.z, v.w};
  f16x4 h, l;
#pragma unroll
  for (int j = 0; j < 4; j++) {
    HL r = split_one(a[j]);
    h[j] = r.h;
    l[j] = r.l;
  }
  dh[i] = h;
  dl[i] = l;
}

// ---------------------------------------------------------------------------
// all weight splits in one launch (scaled x256); W4 padded 160x256 -> 256x256
// ---------------------------------------------------------------------------
__global__ void split_weights(const float* __restrict__ W1, const float* __restrict__ W2,
                              const float* __restrict__ W3, const float* __restrict__ W4,
                              const float* __restrict__ b4,
                              f16x4* __restrict__ W1h, f16x4* __restrict__ W1l,
                              f16x4* __restrict__ W2h, f16x4* __restrict__ W2l,
                              f16x4* __restrict__ W3h, f16x4* __restrict__ W3l,
                              f16x4* __restrict__ W4h, f16x4* __restrict__ W4l,
                              float* __restrict__ b4p) {
  const int blk = blockIdx.x;
  const int tid = threadIdx.x;
  if (blk < 4736) {
    const float4* src;
    f16x4 *dh, *dl;
    int i;
    if (blk < 4096) {
      src = (const float4*)W1; dh = W1h; dl = W1l; i = blk * 256 + tid;
    } else if (blk < 4608) {
      src = (const float4*)W2; dh = W2h; dl = W2l; i = (blk - 4096) * 256 + tid;
    } else {
      src = (const float4*)W3; dh = W3h; dl = W3l; i = (blk - 4608) * 256 + tid;
    }
    float4 v = src[i];
    float a[4] = {v.x * 256.0f, v.y * 256.0f, v.z * 256.0f, v.w * 256.0f};
    f16x4 h, l;
#pragma unroll
    for (int j = 0; j < 4; j++) {
      HL r = split_one(a[j]);
      h[j] = r.h;
      l[j] = r.l;
    }
    dh[i] = h;
    dl[i] = l;
  } else if (blk < 4800) {
    int i = (blk - 4736) * 256 + tid;
    int i4 = i << 2;
    int row = i4 >> 8;
    f16x4 h, l;
#pragma unroll
    for (int j = 0; j < 4; j++) {
      float a = (row < 160) ? W4[i4 + j] * 256.0f : 0.0f;
      HL r = split_one(a);
      h[j] = r.h;
      l[j] = r.l;
    }
    W4h[i] = h;
    W4l[i] = l;
  } else {
    b4p[tid] = (tid < 160) ? b4[tid] : 0.0f;
  }
}

// ---------------------------------------------------------------------------
// R5 fused GEMM (G2-4): fp16x2 split-precision, double-buffered, fused epilogue.
// C[M,N] = A[M,K]*B[N,K]^T (+bias, relu). Tile TM x TN, 256 threads = 4 waves
// (2x2), wave tile (TM/2)x(TN/2) of 16x16x32 MFMAs. One barrier per K32 step.
// ---------------------------------------------------------------------------
template <int TM, int TN, int N, int K, bool RELU, bool SPLIT_OUT>
__global__ void __launch_bounds__(256, 2)
gemm_fused(const _Float16* __restrict__ Ah, const _Float16* __restrict__ Al,
           const _Float16* __restrict__ Bh, const _Float16* __restrict__ Bl,
           const float* __restrict__ bias,
           _Float16* __restrict__ Ch, _Float16* __restrict__ Cl,
           float* __restrict__ Cf) {
  constexpr int AM = TM / 32;
  constexpr int BN = TN / 32;
  constexpr int AU = TM / 8;
  constexpr int TU = (TM + TN) / 8;
  constexpr int UPW = TU / 4;
  constexpr int NK = K / 32;

  __shared__ __align__(16) _Float16 s[2][(TM + TN) * 64];

  const int tid = threadIdx.x;
  const int lane = tid & 63;
  const int w = tid >> 6;
  const int wm = w >> 1, wn = w & 1;
  const int m0 = blockIdx.y * TM;
  const int n0 = blockIdx.x * TN;

  const int srow = lane >> 2;
  const int sk8 = (((lane & 3) - (lane >> 3)) & 3) * 8;

  const _Float16* gb[UPW];
  int lo[UPW];
#pragma unroll
  for (int i = 0; i < UPW; ++i) {
    const int u = w * UPW + i;
    if (u < AU) {
      const int g = u >> 1, hl = u & 1;
      gb[i] = (hl ? Al : Ah) + (size_t)(m0 + g * 16 + srow) * K + sk8;
    } else {
      const int ub = u - AU;
      const int g = ub >> 1, hl = ub & 1;
      gb[i] = (hl ? Bl : Bh) + (size_t)(n0 + g * 16 + srow) * K + sk8;
    }
    lo[i] = u * 512;
  }

  const int fr = lane & 15;
  const int fq = lane >> 4;
  const int fslot8 = (4 * fr + ((fq + (fr >> 1)) & 3)) * 8;

  f32x4 acc1[AM][BN], acc2[AM][BN];
#pragma unroll
  for (int i = 0; i < AM; i++)
#pragma unroll
    for (int j = 0; j < BN; j++) {
      acc1[i][j] = 0.0f;
      acc2[i][j] = 0.0f;
    }

#pragma unroll
  for (int i = 0; i < UPW; ++i) load16_lds(gb[i], &s[0][lo[i]]);

  for (int kt = 0; kt < NK; ++kt) {
    const int cur = kt & 1;
    __syncthreads();

    if (kt + 1 < NK) {
      const int kofs = (kt + 1) * 32;
#pragma unroll
      for (int i = 0; i < UPW; ++i) load16_lds(gb[i] + kofs, &s[cur ^ 1][lo[i]]);
    }

    f16x8 fAh[AM], fAl[AM], fBh[BN], fBl[BN];
#pragma unroll
    for (int im = 0; im < AM; ++im) {
      const int g = wm * AM + im;
      fAh[im] = *(const f16x8*)(&s[cur][(g * 2 + 0) * 512 + fslot8]);
      fAl[im] = *(const f16x8*)(&s[cur][(g * 2 + 1) * 512 + fslot8]);
    }
#pragma unroll
    for (int in = 0; in < BN; ++in) {
      const int g = wn * BN + in;
      fBh[in] = *(const f16x8*)(&s[cur][TM * 64 + (g * 2 + 0) * 512 + fslot8]);
      fBl[in] = *(const f16x8*)(&s[cur][TM * 64 + (g * 2 + 1) * 512 + fslot8]);
    }
#pragma unroll
    for (int im = 0; im < AM; ++im) {
#pragma unroll
      for (int in = 0; in < BN; ++in) {
        acc1[im][in] = __builtin_amdgcn_mfma_f32_16x16x32_f16(fAh[im], fBh[in], acc1[im][in], 0, 0, 0);
        acc2[im][in] = __builtin_amdgcn_mfma_f32_16x16x32_f16(fAh[im], fBl[in], acc2[im][in], 0, 0, 0);
        acc2[im][in] = __builtin_amdgcn_mfma_f32_16x16x32_f16(fAl[im], fBh[in], acc2[im][in], 0, 0, 0);
      }
    }
  }

  const int quad = lane >> 4;
#pragma unroll
  for (int in = 0; in < BN; ++in) {
    const int n = n0 + wn * (TN / 2) + in * 16 + fr;
    const float bv = bias[n];
#pragma unroll
    for (int im = 0; im < AM; ++im) {
#pragma unroll
      for (int r = 0; r < 4; ++r) {
        const int m = m0 + wm * (TM / 2) + im * 16 + quad * 4 + r;
        float c = (acc1[im][in][r] + acc2[im][in][r] * (1.0f / 4096.0f)) * (1.0f / 256.0f) + bv;
        if (RELU) c = fmaxf(c, 0.0f);
        const size_t off = (size_t)m * N + n;
        if (SPLIT_OUT) {
          HL rr = split_one(c);
          Ch[off] = rr.h;
          Cl[off] = rr.l;
        } else {
          Cf[off] = c;
        }
      }
    }
  }
}

// ---------------------------------------------------------------------------
// G1: split-K partial GEMM, counted-vmcnt TRIPLE buffer, 8 waves (2x4 grid).
// Per K32 step: s_waitcnt vmcnt(6) [tile kt landed; tile kt+1 stays in flight]
// -> s_barrier -> issue stage(kt+2) into buf[(kt+2)%3] (read last at kt-1,
// protected by this barrier) -> ds_read frags from buf[kt%3] -> 48 MFMAs.
// Buffer indices are LITERAL (loop tiled x3) -> no runtime LDS addressing.
// ---------------------------------------------------------------------------
#define G1_STEP(BUF, WAITN)                                                    \
  {                                                                            \
    asm volatile("s_waitcnt vmcnt(" #WAITN ")" ::: "memory");                  \
    __builtin_amdgcn_s_barrier();                                              \
    if (kt + 2 < NK) {                                                         \
      const int kofs = (kt + 2) * 32;                                          \
      _Float16* dst = s3 + (((BUF) + 2) % 3) * BUFH;                           \
      _Pragma("unroll") for (int i = 0; i < UPW; ++i)                          \
          load16_lds(gb[i] + kofs, dst + lo[i]);                               \
    }                                                                          \
    const _Float16* sb = s3 + (BUF) * BUFH;                                    \
    f16x8 fBh[BNv], fBl[BNv];                                                  \
    _Pragma("unroll") for (int in = 0; in < BNv; ++in) {                       \
      fBh[in] = *(const f16x8*)(sb + boff + in * 1024);                        \
      fBl[in] = *(const f16x8*)(sb + boff + in * 1024 + 512);                  \
    }                                                                          \
    _Pragma("unroll") for (int im = 0; im < AMv; ++im) {                       \
      f16x8 fAh = *(const f16x8*)(sb + aoff + im * 1024);                      \
      f16x8 fAl = *(const f16x8*)(sb + aoff + im * 1024 + 512);                \
      _Pragma("unroll") for (int in = 0; in < BNv; ++in) {                     \
        acc1[im][in] = __builtin_amdgcn_mfma_f32_16x16x32_f16(fAh, fBh[in], acc1[im][in], 0, 0, 0); \
        acc2[im][in] = __builtin_amdgcn_mfma_f32_16x16x32_f16(fAh, fBl[in], acc2[im][in], 0, 0, 0); \
        acc2[im][in] = __builtin_amdgcn_mfma_f32_16x16x32_f16(fAl, fBh[in], acc2[im][in], 0, 0, 0); \
      }                                                                        \
    }                                                                          \
    ++kt;                                                                      \
  }

template <int TM, int TN, int N, int K, int KSPLIT>
__global__ void __launch_bounds__(512, 2)
gemm_g1_tb(const _Float16* __restrict__ Ah, const _Float16* __restrict__ Al,
           const _Float16* __restrict__ Bh, const _Float16* __restrict__ Bl,
           float* __restrict__ Cp) {
  constexpr int WTM = TM / 2;        // 64: wave tile rows (wave grid 2x4)
  constexpr int WTN = TN / 4;        // 64: wave tile cols
  constexpr int AMv = WTM / 16;      // 4
  constexpr int BNv = WTN / 16;      // 4
  constexpr int AU = TM / 8;         // 16 A units (16 rows x 32 halves, hi/lo)
  constexpr int TU = (TM + TN) / 8;  // 48 total units
  constexpr int UPW = TU / 8;        // 6 staging loads per wave per step
  constexpr int NK = K / KSPLIT / 32;
  constexpr int BUFH = TU * 512;     // halves per buffer (24576)
  static_assert((NK - 1) % 3 == 0, "K-loop x3 tiling requires NK = 3m+1");

  __shared__ __align__(16) _Float16 s3[3 * BUFH];  // 144 KB

  const int tid = threadIdx.x;
  const int lane = tid & 63;
  const int w = tid >> 6;   // 0..7
  const int wm = w >> 2;    // 0..1
  const int wn = w & 3;     // 0..3
  const int m0 = blockIdx.y * TM;
  const int n0 = blockIdx.x * TN;
  const int kb = blockIdx.z * (K / KSPLIT);

  // staging swizzle (R4-verified): lane -> row lane>>2, chunk ((lane&3)-(lane>>3))&3
  const int srow = lane >> 2;
  const int sk8 = (((lane & 3) - (lane >> 3)) & 3) * 8;

  const _Float16* gb[UPW];
  int lo[UPW];
#pragma unroll
  for (int i = 0; i < UPW; ++i) {
    const int u = w * UPW + i;
    if (u < AU) {
      const int g = u >> 1, hl = u & 1;
      gb[i] = (hl ? Al : Ah) + (size_t)(m0 + g * 16 + srow) * K + kb + sk8;
    } else {
      const int ub = u - AU;
      const int g = ub >> 1, hl = ub & 1;
      gb[i] = (hl ? Bl : Bh) + (size_t)(n0 + g * 16 + srow) * K + kb + sk8;
    }
    lo[i] = u * 512;
  }

  // fragment-read swizzled lane offset (R4-verified)
  const int fr = lane & 15;
  const int fq = lane >> 4;
  const int fslot8 = (4 * fr + ((fq + (fr >> 1)) & 3)) * 8;

  // per-wave frag base offsets within a buffer (halves)
  const int aoff = wm * (AMv * 1024) + fslot8;             // A region [0, AU*512)
  const int boff = AU * 512 + wn * (BNv * 1024) + fslot8;  // B region

  f32x4 acc1[AMv][BNv], acc2[AMv][BNv];
#pragma unroll
  for (int i = 0; i < AMv; i++)
#pragma unroll
    for (int j = 0; j < BNv; j++) {
      acc1[i][j] = 0.0f;
      acc2[i][j] = 0.0f;
    }

  // prologue: tiles 0,1 -> buffers 0,1 (12 loads in flight)
#pragma unroll
  for (int i = 0; i < UPW; ++i) load16_lds(gb[i], s3 + lo[i]);
#pragma unroll
  for (int i = 0; i < UPW; ++i) load16_lds(gb[i] + 32, s3 + BUFH + lo[i]);

  int kt = 0;
#pragma unroll 1
  for (int j = 0; j < (NK - 1) / 3; ++j) {
    G1_STEP(0, 6)
    G1_STEP(1, 6)
    G1_STEP(2, 6)
  }
  G1_STEP(0, 0)  // kt == NK-1: final tile, full drain, no stage

  // epilogue: raw f32 partial. C/D layout col=lane&15, row=quad*4+reg
  const int quad = lane >> 4;
  float* Cz = Cp + (size_t)blockIdx.z * ((size_t)gridDim.y * TM) * N;
#pragma unroll
  for (int in = 0; in < BNv; ++in) {
    const int n = n0 + wn * WTN + in * 16 + fr;
#pragma unroll
    for (int im = 0; im < AMv; ++im) {
#pragma unroll
      for (int r = 0; r < 4; ++r) {
        const int m = m0 + wm * WTM + im * 16 + quad * 4 + r;
        Cz[(size_t)m * N + n] = acc1[im][in][r] + acc2[im][in][r] * (1.0f / 4096.0f);
      }
    }
  }
}

// ---------------------------------------------------------------------------
// combine: c = (p0 + p1) * (1/256) + bias[n]; relu; split f16 out. (R8-verified)
// ---------------------------------------------------------------------------
__global__ void __launch_bounds__(256)
combine1(const float* __restrict__ Cp, const float* __restrict__ bias, int N,
         size_t halfN, _Float16* __restrict__ Ch, _Float16* __restrict__ Cl) {
  const size_t i4 = ((size_t)blockIdx.x * 256 + threadIdx.x) * 4;
  float4 p0 = *(const float4*)(Cp + i4);
  float4 p1 = *(const float4*)(Cp + halfN + i4);
  float4 bv = *(const float4*)(bias + (i4 % (size_t)N));
  float c[4] = {(p0.x + p1.x) * (1.0f / 256.0f) + bv.x,
                (p0.y + p1.y) * (1.0f / 256.0f) + bv.y,
                (p0.z + p1.z) * (1.0f / 256.0f) + bv.z,
                (p0.w + p1.w) * (1.0f / 256.0f) + bv.w};
  f16x4 h, l;
#pragma unroll
  for (int j = 0; j < 4; j++) {
    c[j] = fmaxf(c[j], 0.0f);
    HL r = split_one(c[j]);
    h[j] = r.h;
    l[j] = r.l;
  }
  *(f16x4*)(Ch + i4) = h;
  *(f16x4*)(Cl + i4) = l;
}

// ---------------------------------------------------------------------------
// Gabor synthesis: one block per batch; thread owns 8 contiguous t samples,
// per-wavelet wave-uniform 5-sigma window skip.
// ---------------------------------------------------------------------------
__global__ void __launch_bounds__(256)
synth(const float* __restrict__ P, float* __restrict__ out) {
  __shared__ float sA[NWAV], sT0[NWAV], sF[NWAV], sC[NWAV], sPh[NWAV], sSg[NWAV];
  const int b = blockIdx.x;
  const int tid = threadIdx.x;
  if (tid < NWAV) {
    const float* q = P + (size_t)b * 256 + tid * 5;
    const float L2E = 1.44269504088896340736f;
    float A = q[0], p1 = q[1], p2 = q[2], p3 = q[3], p4 = q[4];
    float s1 = 1.0f / (1.0f + exp2f(-p1 * L2E));
    float s2 = 1.0f / (1.0f + exp2f(-p2 * L2E));
    float s3 = 1.0f / (1.0f + exp2f(-p3 * L2E));
    float sg = s3 * 200.0f + 2.0f;
    sA[tid] = A;
    sT0[tid] = s1 * 2048.0f;
    sF[tid] = s2 * 0.5f;
    sC[tid] = -L2E / (2.0f * sg * sg);
    sPh[tid] = p4 * 0.15915494309189535f;
    sSg[tid] = sg;
  }
  __syncthreads();

  const float t0f = (float)(tid * 8);
  const int wlo = (tid & ~63) * 8;
  float acc[8];
#pragma unroll
  for (int i = 0; i < 8; i++) acc[i] = 0.0f;

  for (int wv = 0; wv < NWAV; wv++) {
    const float t0 = sT0[wv], sg = sSg[wv];
    if (t0 + 5.0f * sg < (float)wlo || t0 - 5.0f * sg > (float)(wlo + 511)) continue;
    const float A = sA[wv], fr = sF[wv], cn = sC[wv], ph = sPh[wv];
#pragma unroll
    for (int i = 0; i < 8; i++) {
      float dt = (t0f + (float)i) - t0;
      float e = exp2f(dt * dt * cn);
      float r = fr * dt + ph;
      r -= floorf(r);
      float cs = __builtin_amdgcn_cosf(r);
      acc[i] += A * e * cs;
    }
  }

  float* o = out + (size_t)b * (2 * SIGNAL_LEN) + tid * 8;
  float4 v0 = make_float4(acc[0], acc[1], acc[2], acc[3]);
  float4 v1 = make_float4(acc[4], acc[5], acc[6], acc[7]);
  *(float4*)(o) = v0;
  *(float4*)(o + 4) = v1;
  *(float4*)(o + SIGNAL_LEN) = v0;
  *(float4*)(o + SIGNAL_LEN + 4) = v1;
}

// ---------------------------------------------------------------------------
extern "C" void kernel_launch(void* const* d_in, const int* in_sizes, int n_in,
                              void* d_out, int out_size, void* d_ws, size_t ws_size,
                              hipStream_t stream) {
  (void)in_sizes; (void)n_in; (void)out_size; (void)ws_size;
  const float* X  = (const float*)d_in[0];
  const float* W1 = (const float*)d_in[1];
  const float* b1 = (const float*)d_in[2];
  const float* W2 = (const float*)d_in[3];
  const float* b2 = (const float*)d_in[4];
  const float* W3 = (const float*)d_in[5];
  const float* b3 = (const float*)d_in[6];
  const float* W4 = (const float*)d_in[7];
  const float* b4 = (const float*)d_in[8];
  float* out = (float*)d_out;

  char* p = (char*)d_ws;
  auto take = [&](size_t bytes) -> char* {
    char* r = p;
    p += (bytes + 255) & ~(size_t)255;
    return r;
  };
  _Float16* Xh  = (_Float16*)take((size_t)4096 * 4096 * 2);
  _Float16* Xl  = (_Float16*)take((size_t)4096 * 4096 * 2);
  _Float16* W1h = (_Float16*)take((size_t)1024 * 4096 * 2);
  _Float16* W1l = (_Float16*)take((size_t)1024 * 4096 * 2);
  _Float16* H1h = (_Float16*)take((size_t)4096 * 1024 * 2);
  _Float16* H1l = (_Float16*)take((size_t)4096 * 1024 * 2);
  _Float16* W2h = (_Float16*)take((size_t)512 * 1024 * 2);
  _Float16* W2l = (_Float16*)take((size_t)512 * 1024 * 2);
  _Float16* H2h = (_Float16*)take((size_t)4096 * 512 * 2);
  _Float16* H2l = (_Float16*)take((size_t)4096 * 512 * 2);
  _Float16* W3h = (_Float16*)take((size_t)256 * 512 * 2);
  _Float16* W3l = (_Float16*)take((size_t)256 * 512 * 2);
  _Float16* H3h = (_Float16*)take((size_t)4096 * 256 * 2);
  _Float16* H3l = (_Float16*)take((size_t)4096 * 256 * 2);
  _Float16* W4h = (_Float16*)take((size_t)256 * 256 * 2);
  _Float16* W4l = (_Float16*)take((size_t)256 * 256 * 2);
  float*    b4p = (float*)take(256 * 4);
  float*    Pp  = (float*)take((size_t)4096 * 256 * 4);
  float*    Cp  = (float*)take((size_t)2 * 4096 * 1024 * 4);  // G1 split-K partials

  split_x<<<16384, 256, 0, stream>>>((const float4*)X, (f16x4*)Xh, (f16x4*)Xl);
  split_weights<<<4801, 256, 0, stream>>>(W1, W2, W3, W4, b4,
                                          (f16x4*)W1h, (f16x4*)W1l, (f16x4*)W2h, (f16x4*)W2l,
                                          (f16x4*)W3h, (f16x4*)W3l, (f16x4*)W4h, (f16x4*)W4l, b4p);

  // G1: 128x256 tile, 8 waves, triple-buffer counted-vmcnt, splitK=2 -> 256 blocks
  gemm_g1_tb<128, 256, 1024, 4096, 2><<<dim3(4, 32, 2), 512, 0, stream>>>(
      Xh, Xl, W1h, W1l, Cp);
  combine1<<<4096, 256, 0, stream>>>(Cp, b1, 1024, (size_t)4096 * 1024, H1h, H1l);

  // G2-4: fused kernels, halved tiles -> 512 blocks = 2 blocks/CU (R11-exact)
  gemm_fused<64, 64, 512, 1024, true, true><<<dim3(8, 64), 256, 0, stream>>>(
      H1h, H1l, W2h, W2l, b2, H2h, H2l, nullptr);
  gemm_fused<32, 64, 256, 512, true, true><<<dim3(4, 128), 256, 0, stream>>>(
      H2h, H2l, W3h, W3l, b3, H3h, H3l, nullptr);
  gemm_fused<32, 64, 256, 256, false, false><<<dim3(4, 128), 256, 0, stream>>>(
      H3h, H3l, W4h, W4l, b4p, nullptr, nullptr, Pp);

  synth<<<4096, 256, 0, stream>>>(Pp, out);
}

// Round 8
// 450.485 us; speedup vs baseline: 1.0171x; 1.0171x over previous
//
#include <hip/hip_runtime.h>

// GaborAutoencoder on MI355X (gfx950)
// split fp32 -> fp16 (hi, lo*4096) -> 3-pass split-precision MFMA GEMMs -> Gabor synth.
// R13 == R12 with the VGPR budget fixed: __launch_bounds__(512, 1) (was (512,2),
//      which capped the allocator at 128 VGPR while the kernel needs ~200 ->
//      scratch spill: WRITE_SIZE +15GB, FETCH +90GB, MfmaUtil 24%). LDS 144KB
//      already limits to 1 block/CU (8 waves = 2/SIMD), so the bound change
//      costs no occupancy. Pipeline structure verified correct in R12 (passed,
//      bank-conflict 0): triple-buffer counted-vmcnt (T4, depth-2, vmcnt(6)
//      never-drain), static literal buffer indices via x3-tiled K-loop.
//      G2-4 / splits / combine1 / synth: R11-exact (banked 395.5us).

#define SIGNAL_LEN 2048
#define NWAV 32

typedef _Float16 f16x8 __attribute__((ext_vector_type(8)));
typedef _Float16 f16x4 __attribute__((ext_vector_type(4)));
typedef float    f32x4 __attribute__((ext_vector_type(4)));

__device__ __forceinline__ void load16_lds(const _Float16* g, _Float16* l) {
  __builtin_amdgcn_global_load_lds((const __attribute__((address_space(1))) void*)g,
                                   (__attribute__((address_space(3))) void*)l,
                                   16, 0, 0);
}

struct HL { _Float16 h, l; };
__device__ __forceinline__ HL split_one(float a) {
  HL r;
  r.h = (_Float16)a;
  r.l = (_Float16)((a - (float)r.h) * 4096.0f);
  return r;
}

// ---------------------------------------------------------------------------
// X split: fp32 float4 -> hi/lo f16x4
// ---------------------------------------------------------------------------
__global__ void split_x(const float4* __restrict__ src, f16x4* __restrict__ dh,
                        f16x4* __restrict__ dl) {
  int i = blockIdx.x * 256 + threadIdx.x;  // 4194304 float4s
  float4 v = src[i];
  float a[4] = {v.x, v.y, v.z, v.w};
  f16x4 h, l;
#pragma unroll
  for (int j = 0; j < 4; j++) {
    HL r = split_one(a[j]);
    h[j] = r.h;
    l[j] = r.l;
  }
  dh[i] = h;
  dl[i] = l;
}

// ---------------------------------------------------------------------------
// all weight splits in one launch (scaled x256); W4 padded 160x256 -> 256x256
// ---------------------------------------------------------------------------
__global__ void split_weights(const float* __restrict__ W1, const float* __restrict__ W2,
                              const float* __restrict__ W3, const float* __restrict__ W4,
                              const float* __restrict__ b4,
                              f16x4* __restrict__ W1h, f16x4* __restrict__ W1l,
                              f16x4* __restrict__ W2h, f16x4* __restrict__ W2l,
                              f16x4* __restrict__ W3h, f16x4* __restrict__ W3l,
                              f16x4* __restrict__ W4h, f16x4* __restrict__ W4l,
                              float* __restrict__ b4p) {
  const int blk = blockIdx.x;
  const int tid = threadIdx.x;
  if (blk < 4736) {
    const float4* src;
    f16x4 *dh, *dl;
    int i;
    if (blk < 4096) {
      src = (const float4*)W1; dh = W1h; dl = W1l; i = blk * 256 + tid;
    } else if (blk < 4608) {
      src = (const float4*)W2; dh = W2h; dl = W2l; i = (blk - 4096) * 256 + tid;
    } else {
      src = (const float4*)W3; dh = W3h; dl = W3l; i = (blk - 4608) * 256 + tid;
    }
    float4 v = src[i];
    float a[4] = {v.x * 256.0f, v.y * 256.0f, v.z * 256.0f, v.w * 256.0f};
    f16x4 h, l;
#pragma unroll
    for (int j = 0; j < 4; j++) {
      HL r = split_one(a[j]);
      h[j] = r.h;
      l[j] = r.l;
    }
    dh[i] = h;
    dl[i] = l;
  } else if (blk < 4800) {
    int i = (blk - 4736) * 256 + tid;
    int i4 = i << 2;
    int row = i4 >> 8;
    f16x4 h, l;
#pragma unroll
    for (int j = 0; j < 4; j++) {
      float a = (row < 160) ? W4[i4 + j] * 256.0f : 0.0f;
      HL r = split_one(a);
      h[j] = r.h;
      l[j] = r.l;
    }
    W4h[i] = h;
    W4l[i] = l;
  } else {
    b4p[tid] = (tid < 160) ? b4[tid] : 0.0f;
  }
}

// ---------------------------------------------------------------------------
// R5 fused GEMM (G2-4): fp16x2 split-precision, double-buffered, fused epilogue.
// C[M,N] = A[M,K]*B[N,K]^T (+bias, relu). Tile TM x TN, 256 threads = 4 waves
// (2x2), wave tile (TM/2)x(TN/2) of 16x16x32 MFMAs. One barrier per K32 step.
// ---------------------------------------------------------------------------
template <int TM, int TN, int N, int K, bool RELU, bool SPLIT_OUT>
__global__ void __launch_bounds__(256, 2)
gemm_fused(const _Float16* __restrict__ Ah, const _Float16* __restrict__ Al,
           const _Float16* __restrict__ Bh, const _Float16* __restrict__ Bl,
           const float* __restrict__ bias,
           _Float16* __restrict__ Ch, _Float16* __restrict__ Cl,
           float* __restrict__ Cf) {
  constexpr int AM = TM / 32;
  constexpr int BN = TN / 32;
  constexpr int AU = TM / 8;
  constexpr int TU = (TM + TN) / 8;
  constexpr int UPW = TU / 4;
  constexpr int NK = K / 32;

  __shared__ __align__(16) _Float16 s[2][(TM + TN) * 64];

  const int tid = threadIdx.x;
  const int lane = tid & 63;
  const int w = tid >> 6;
  const int wm = w >> 1, wn = w & 1;
  const int m0 = blockIdx.y * TM;
  const int n0 = blockIdx.x * TN;

  const int srow = lane >> 2;
  const int sk8 = (((lane & 3) - (lane >> 3)) & 3) * 8;

  const _Float16* gb[UPW];
  int lo[UPW];
#pragma unroll
  for (int i = 0; i < UPW; ++i) {
    const int u = w * UPW + i;
    if (u < AU) {
      const int g = u >> 1, hl = u & 1;
      gb[i] = (hl ? Al : Ah) + (size_t)(m0 + g * 16 + srow) * K + sk8;
    } else {
      const int ub = u - AU;
      const int g = ub >> 1, hl = ub & 1;
      gb[i] = (hl ? Bl : Bh) + (size_t)(n0 + g * 16 + srow) * K + sk8;
    }
    lo[i] = u * 512;
  }

  const int fr = lane & 15;
  const int fq = lane >> 4;
  const int fslot8 = (4 * fr + ((fq + (fr >> 1)) & 3)) * 8;

  f32x4 acc1[AM][BN], acc2[AM][BN];
#pragma unroll
  for (int i = 0; i < AM; i++)
#pragma unroll
    for (int j = 0; j < BN; j++) {
      acc1[i][j] = 0.0f;
      acc2[i][j] = 0.0f;
    }

#pragma unroll
  for (int i = 0; i < UPW; ++i) load16_lds(gb[i], &s[0][lo[i]]);

  for (int kt = 0; kt < NK; ++kt) {
    const int cur = kt & 1;
    __syncthreads();

    if (kt + 1 < NK) {
      const int kofs = (kt + 1) * 32;
#pragma unroll
      for (int i = 0; i < UPW; ++i) load16_lds(gb[i] + kofs, &s[cur ^ 1][lo[i]]);
    }

    f16x8 fAh[AM], fAl[AM], fBh[BN], fBl[BN];
#pragma unroll
    for (int im = 0; im < AM; ++im) {
      const int g = wm * AM + im;
      fAh[im] = *(const f16x8*)(&s[cur][(g * 2 + 0) * 512 + fslot8]);
      fAl[im] = *(const f16x8*)(&s[cur][(g * 2 + 1) * 512 + fslot8]);
    }
#pragma unroll
    for (int in = 0; in < BN; ++in) {
      const int g = wn * BN + in;
      fBh[in] = *(const f16x8*)(&s[cur][TM * 64 + (g * 2 + 0) * 512 + fslot8]);
      fBl[in] = *(const f16x8*)(&s[cur][TM * 64 + (g * 2 + 1) * 512 + fslot8]);
    }
#pragma unroll
    for (int im = 0; im < AM; ++im) {
#pragma unroll
      for (int in = 0; in < BN; ++in) {
        acc1[im][in] = __builtin_amdgcn_mfma_f32_16x16x32_f16(fAh[im], fBh[in], acc1[im][in], 0, 0, 0);
        acc2[im][in] = __builtin_amdgcn_mfma_f32_16x16x32_f16(fAh[im], fBl[in], acc2[im][in], 0, 0, 0);
        acc2[im][in] = __builtin_amdgcn_mfma_f32_16x16x32_f16(fAl[im], fBh[in], acc2[im][in], 0, 0, 0);
      }
    }
  }

  const int quad = lane >> 4;
#pragma unroll
  for (int in = 0; in < BN; ++in) {
    const int n = n0 + wn * (TN / 2) + in * 16 + fr;
    const float bv = bias[n];
#pragma unroll
    for (int im = 0; im < AM; ++im) {
#pragma unroll
      for (int r = 0; r < 4; ++r) {
        const int m = m0 + wm * (TM / 2) + im * 16 + quad * 4 + r;
        float c = (acc1[im][in][r] + acc2[im][in][r] * (1.0f / 4096.0f)) * (1.0f / 256.0f) + bv;
        if (RELU) c = fmaxf(c, 0.0f);
        const size_t off = (size_t)m * N + n;
        if (SPLIT_OUT) {
          HL rr = split_one(c);
          Ch[off] = rr.h;
          Cl[off] = rr.l;
        } else {
          Cf[off] = c;
        }
      }
    }
  }
}

// ---------------------------------------------------------------------------
// G1: split-K partial GEMM, counted-vmcnt TRIPLE buffer, 8 waves (2x4 grid).
// Per K32 step: s_waitcnt vmcnt(6) [tile kt landed; tile kt+1 stays in flight]
// -> s_barrier -> issue stage(kt+2) into buf[(kt+2)%3] (read last at kt-1,
// protected by this barrier) -> ds_read frags from buf[kt%3] -> 48 MFMAs.
// Buffer indices are LITERAL (loop tiled x3) -> no runtime LDS addressing.
// ---------------------------------------------------------------------------
#define G1_STEP(BUF, WAITN)                                                    \
  {                                                                            \
    asm volatile("s_waitcnt vmcnt(" #WAITN ")" ::: "memory");                  \
    __builtin_amdgcn_s_barrier();                                              \
    if (kt + 2 < NK) {                                                         \
      const int kofs = (kt + 2) * 32;                                          \
      _Float16* dst = s3 + (((BUF) + 2) % 3) * BUFH;                           \
      _Pragma("unroll") for (int i = 0; i < UPW; ++i)                          \
          load16_lds(gb[i] + kofs, dst + lo[i]);                               \
    }                                                                          \
    const _Float16* sb = s3 + (BUF) * BUFH;                                    \
    f16x8 fBh[BNv], fBl[BNv];                                                  \
    _Pragma("unroll") for (int in = 0; in < BNv; ++in) {                       \
      fBh[in] = *(const f16x8*)(sb + boff + in * 1024);                        \
      fBl[in] = *(const f16x8*)(sb + boff + in * 1024 + 512);                  \
    }                                                                          \
    _Pragma("unroll") for (int im = 0; im < AMv; ++im) {                       \
      f16x8 fAh = *(const f16x8*)(sb + aoff + im * 1024);                      \
      f16x8 fAl = *(const f16x8*)(sb + aoff + im * 1024 + 512);                \
      _Pragma("unroll") for (int in = 0; in < BNv; ++in) {                     \
        acc1[im][in] = __builtin_amdgcn_mfma_f32_16x16x32_f16(fAh, fBh[in], acc1[im][in], 0, 0, 0); \
        acc2[im][in] = __builtin_amdgcn_mfma_f32_16x16x32_f16(fAh, fBl[in], acc2[im][in], 0, 0, 0); \
        acc2[im][in] = __builtin_amdgcn_mfma_f32_16x16x32_f16(fAl, fBh[in], acc2[im][in], 0, 0, 0); \
      }                                                                        \
    }                                                                          \
    ++kt;                                                                      \
  }

template <int TM, int TN, int N, int K, int KSPLIT>
__global__ void __launch_bounds__(512, 1)
gemm_g1_tb(const _Float16* __restrict__ Ah, const _Float16* __restrict__ Al,
           const _Float16* __restrict__ Bh, const _Float16* __restrict__ Bl,
           float* __restrict__ Cp) {
  constexpr int WTM = TM / 2;        // 64: wave tile rows (wave grid 2x4)
  constexpr int WTN = TN / 4;        // 64: wave tile cols
  constexpr int AMv = WTM / 16;      // 4
  constexpr int BNv = WTN / 16;      // 4
  constexpr int AU = TM / 8;         // 16 A units (16 rows x 32 halves, hi/lo)
  constexpr int TU = (TM + TN) / 8;  // 48 total units
  constexpr int UPW = TU / 8;        // 6 staging loads per wave per step
  constexpr int NK = K / KSPLIT / 32;
  constexpr int BUFH = TU * 512;     // halves per buffer (24576)
  static_assert((NK - 1) % 3 == 0, "K-loop x3 tiling requires NK = 3m+1");

  __shared__ __align__(16) _Float16 s3[3 * BUFH];  // 144 KB

  const int tid = threadIdx.x;
  const int lane = tid & 63;
  const int w = tid >> 6;   // 0..7
  const int wm = w >> 2;    // 0..1
  const int wn = w & 3;     // 0..3
  const int m0 = blockIdx.y * TM;
  const int n0 = blockIdx.x * TN;
  const int kb = blockIdx.z * (K / KSPLIT);

  // staging swizzle (R4-verified): lane -> row lane>>2, chunk ((lane&3)-(lane>>3))&3
  const int srow = lane >> 2;
  const int sk8 = (((lane & 3) - (lane >> 3)) & 3) * 8;

  const _Float16* gb[UPW];
  int lo[UPW];
#pragma unroll
  for (int i = 0; i < UPW; ++i) {
    const int u = w * UPW + i;
    if (u < AU) {
      const int g = u >> 1, hl = u & 1;
      gb[i] = (hl ? Al : Ah) + (size_t)(m0 + g * 16 + srow) * K + kb + sk8;
    } else {
      const int ub = u - AU;
      const int g = ub >> 1, hl = ub & 1;
      gb[i] = (hl ? Bl : Bh) + (size_t)(n0 + g * 16 + srow) * K + kb + sk8;
    }
    lo[i] = u * 512;
  }

  // fragment-read swizzled lane offset (R4-verified)
  const int fr = lane & 15;
  const int fq = lane >> 4;
  const int fslot8 = (4 * fr + ((fq + (fr >> 1)) & 3)) * 8;

  // per-wave frag base offsets within a buffer (halves)
  const int aoff = wm * (AMv * 1024) + fslot8;             // A region [0, AU*512)
  const int boff = AU * 512 + wn * (BNv * 1024) + fslot8;  // B region

  f32x4 acc1[AMv][BNv], acc2[AMv][BNv];
#pragma unroll
  for (int i = 0; i < AMv; i++)
#pragma unroll
    for (int j = 0; j < BNv; j++) {
      acc1[i][j] = 0.0f;
      acc2[i][j] = 0.0f;
    }

  // prologue: tiles 0,1 -> buffers 0,1 (12 loads in flight)
#pragma unroll
  for (int i = 0; i < UPW; ++i) load16_lds(gb[i], s3 + lo[i]);
#pragma unroll
  for (int i = 0; i < UPW; ++i) load16_lds(gb[i] + 32, s3 + BUFH + lo[i]);

  int kt = 0;
#pragma unroll 1
  for (int j = 0; j < (NK - 1) / 3; ++j) {
    G1_STEP(0, 6)
    G1_STEP(1, 6)
    G1_STEP(2, 6)
  }
  G1_STEP(0, 0)  // kt == NK-1: final tile, full drain, no stage

  // epilogue: raw f32 partial. C/D layout col=lane&15, row=quad*4+reg
  const int quad = lane >> 4;
  float* Cz = Cp + (size_t)blockIdx.z * ((size_t)gridDim.y * TM) * N;
#pragma unroll
  for (int in = 0; in < BNv; ++in) {
    const int n = n0 + wn * WTN + in * 16 + fr;
#pragma unroll
    for (int im = 0; im < AMv; ++im) {
#pragma unroll
      for (int r = 0; r < 4; ++r) {
        const int m = m0 + wm * WTM + im * 16 + quad * 4 + r;
        Cz[(size_t)m * N + n] = acc1[im][in][r] + acc2[im][in][r] * (1.0f / 4096.0f);
      }
    }
  }
}

// ---------------------------------------------------------------------------
// combine: c = (p0 + p1) * (1/256) + bias[n]; relu; split f16 out. (R8-verified)
// ---------------------------------------------------------------------------
__global__ void __launch_bounds__(256)
combine1(const float* __restrict__ Cp, const float* __restrict__ bias, int N,
         size_t halfN, _Float16* __restrict__ Ch, _Float16* __restrict__ Cl) {
  const size_t i4 = ((size_t)blockIdx.x * 256 + threadIdx.x) * 4;
  float4 p0 = *(const float4*)(Cp + i4);
  float4 p1 = *(const float4*)(Cp + halfN + i4);
  float4 bv = *(const float4*)(bias + (i4 % (size_t)N));
  float c[4] = {(p0.x + p1.x) * (1.0f / 256.0f) + bv.x,
                (p0.y + p1.y) * (1.0f / 256.0f) + bv.y,
                (p0.z + p1.z) * (1.0f / 256.0f) + bv.z,
                (p0.w + p1.w) * (1.0f / 256.0f) + bv.w};
  f16x4 h, l;
#pragma unroll
  for (int j = 0; j < 4; j++) {
    c[j] = fmaxf(c[j], 0.0f);
    HL r = split_one(c[j]);
    h[j] = r.h;
    l[j] = r.l;
  }
  *(f16x4*)(Ch + i4) = h;
  *(f16x4*)(Cl + i4) = l;
}

// ---------------------------------------------------------------------------
// Gabor synthesis: one block per batch; thread owns 8 contiguous t samples,
// per-wavelet wave-uniform 5-sigma window skip.
// ---------------------------------------------------------------------------
__global__ void __launch_bounds__(256)
synth(const float* __restrict__ P, float* __restrict__ out) {
  __shared__ float sA[NWAV], sT0[NWAV], sF[NWAV], sC[NWAV], sPh[NWAV], sSg[NWAV];
  const int b = blockIdx.x;
  const int tid = threadIdx.x;
  if (tid < NWAV) {
    const float* q = P + (size_t)b * 256 + tid * 5;
    const float L2E = 1.44269504088896340736f;
    float A = q[0], p1 = q[1], p2 = q[2], p3 = q[3], p4 = q[4];
    float s1 = 1.0f / (1.0f + exp2f(-p1 * L2E));
    float s2 = 1.0f / (1.0f + exp2f(-p2 * L2E));
    float s3 = 1.0f / (1.0f + exp2f(-p3 * L2E));
    float sg = s3 * 200.0f + 2.0f;
    sA[tid] = A;
    sT0[tid] = s1 * 2048.0f;
    sF[tid] = s2 * 0.5f;
    sC[tid] = -L2E / (2.0f * sg * sg);
    sPh[tid] = p4 * 0.15915494309189535f;
    sSg[tid] = sg;
  }
  __syncthreads();

  const float t0f = (float)(tid * 8);
  const int wlo = (tid & ~63) * 8;
  float acc[8];
#pragma unroll
  for (int i = 0; i < 8; i++) acc[i] = 0.0f;

  for (int wv = 0; wv < NWAV; wv++) {
    const float t0 = sT0[wv], sg = sSg[wv];
    if (t0 + 5.0f * sg < (float)wlo || t0 - 5.0f * sg > (float)(wlo + 511)) continue;
    const float A = sA[wv], fr = sF[wv], cn = sC[wv], ph = sPh[wv];
#pragma unroll
    for (int i = 0; i < 8; i++) {
      float dt = (t0f + (float)i) - t0;
      float e = exp2f(dt * dt * cn);
      float r = fr * dt + ph;
      r -= floorf(r);
      float cs = __builtin_amdgcn_cosf(r);
      acc[i] += A * e * cs;
    }
  }

  float* o = out + (size_t)b * (2 * SIGNAL_LEN) + tid * 8;
  float4 v0 = make_float4(acc[0], acc[1], acc[2], acc[3]);
  float4 v1 = make_float4(acc[4], acc[5], acc[6], acc[7]);
  *(float4*)(o) = v0;
  *(float4*)(o + 4) = v1;
  *(float4*)(o + SIGNAL_LEN) = v0;
  *(float4*)(o + SIGNAL_LEN + 4) = v1;
}

// ---------------------------------------------------------------------------
extern "C" void kernel_launch(void* const* d_in, const int* in_sizes, int n_in,
                              void* d_out, int out_size, void* d_ws, size_t ws_size,
                              hipStream_t stream) {
  (void)in_sizes; (void)n_in; (void)out_size; (void)ws_size;
  const float* X  = (const float*)d_in[0];
  const float* W1 = (const float*)d_in[1];
  const float* b1 = (const float*)d_in[2];
  const float* W2 = (const float*)d_in[3];
  const float* b2 = (const float*)d_in[4];
  const float* W3 = (const float*)d_in[5];
  const float* b3 = (const float*)d_in[6];
  const float* W4 = (const float*)d_in[7];
  const float* b4 = (const float*)d_in[8];
  float* out = (float*)d_out;

  char* p = (char*)d_ws;
  auto take = [&](size_t bytes) -> char* {
    char* r = p;
    p += (bytes + 255) & ~(size_t)255;
    return r;
  };
  _Float16* Xh  = (_Float16*)take((size_t)4096 * 4096 * 2);
  _Float16* Xl  = (_Float16*)take((size_t)4096 * 4096 * 2);
  _Float16* W1h = (_Float16*)take((size_t)1024 * 4096 * 2);
  _Float16* W1l = (_Float16*)take((size_t)1024 * 4096 * 2);
  _Float16* H1h = (_Float16*)take((size_t)4096 * 1024 * 2);
  _Float16* H1l = (_Float16*)take((size_t)4096 * 1024 * 2);
  _Float16* W2h = (_Float16*)take((size_t)512 * 1024 * 2);
  _Float16* W2l = (_Float16*)take((size_t)512 * 1024 * 2);
  _Float16* H2h = (_Float16*)take((size_t)4096 * 512 * 2);
  _Float16* H2l = (_Float16*)take((size_t)4096 * 512 * 2);
  _Float16* W3h = (_Float16*)take((size_t)256 * 512 * 2);
  _Float16* W3l = (_Float16*)take((size_t)256 * 512 * 2);
  _Float16* H3h = (_Float16*)take((size_t)4096 * 256 * 2);
  _Float16* H3l = (_Float16*)take((size_t)4096 * 256 * 2);
  _Float16* W4h = (_Float16*)take((size_t)256 * 256 * 2);
  _Float16* W4l = (_Float16*)take((size_t)256 * 256 * 2);
  float*    b4p = (float*)take(256 * 4);
  float*    Pp  = (float*)take((size_t)4096 * 256 * 4);
  float*    Cp  = (float*)take((size_t)2 * 4096 * 1024 * 4);  // G1 split-K partials

  split_x<<<16384, 256, 0, stream>>>((const float4*)X, (f16x4*)Xh, (f16x4*)Xl);
  split_weights<<<4801, 256, 0, stream>>>(W1, W2, W3, W4, b4,
                                          (f16x4*)W1h, (f16x4*)W1l, (f16x4*)W2h, (f16x4*)W2l,
                                          (f16x4*)W3h, (f16x4*)W3l, (f16x4*)W4h, (f16x4*)W4l, b4p);

  // G1: 128x256 tile, 8 waves, triple-buffer counted-vmcnt, splitK=2 -> 256 blocks
  gemm_g1_tb<128, 256, 1024, 4096, 2><<<dim3(4, 32, 2), 512, 0, stream>>>(
      Xh, Xl, W1h, W1l, Cp);
  combine1<<<4096, 256, 0, stream>>>(Cp, b1, 1024, (size_t)4096 * 1024, H1h, H1l);

  // G2-4: fused kernels, halved tiles -> 512 blocks = 2 blocks/CU (R11-exact)
  gemm_fused<64, 64, 512, 1024, true, true><<<dim3(8, 64), 256, 0, stream>>>(
      H1h, H1l, W2h, W2l, b2, H2h, H2l, nullptr);
  gemm_fused<32, 64, 256, 512, true, true><<<dim3(4, 128), 256, 0, stream>>>(
      H2h, H2l, W3h, W3l, b3, H3h, H3l, nullptr);
  gemm_fused<32, 64, 256, 256, false, false><<<dim3(4, 128), 256, 0, stream>>>(
      H3h, H3l, W4h, W4l, b4p, nullptr, nullptr, Pp);

  synth<<<4096, 256, 0, stream>>>(Pp, out);
}

// Round 9
// 388.949 us; speedup vs baseline: 1.1781x; 1.1582x over previous
//
#include <hip/hip_runtime.h>

// GaborAutoencoder on MI355X (gfx950)
// split fp32 -> fp16 (hi, lo*4096) -> 3-pass split-precision MFMA GEMMs -> Gabor synth.
// R14: deep-pipeline branch abandoned (R6/R12/R13 all lost to the simple loop;
//      R13's launch_bounds fix was a no-op: VGPR stayed 128, spill remained).
//      G1 reverted to R9-exact gemm_part (banked R11 = 395.5us) PLUS
//      T1 XCD-aware block swizzle (1-D launch, decode xcd=f&7 -> x=xcd>>1,
//      z=xcd&1, y=f>>3): all 32 y-blocks sharing one (x,z) B-panel (2MB,
//      L2-fit) land on ONE XCD -> B fetched once per XCD, staging B-loads
//      become L2 hits, shorter exposed drain. G2 likewise (same-y blocks share
//      a 256KB A-panel: y=xcd*8+(slot>>3), x=slot&7). Bijective decodes.
//      G3/G4 / splits / combine1 / synth: R11-exact.

#define SIGNAL_LEN 2048
#define NWAV 32

typedef _Float16 f16x8 __attribute__((ext_vector_type(8)));
typedef _Float16 f16x4 __attribute__((ext_vector_type(4)));
typedef float    f32x4 __attribute__((ext_vector_type(4)));

__device__ __forceinline__ void load16_lds(const _Float16* g, _Float16* l) {
  __builtin_amdgcn_global_load_lds((const __attribute__((address_space(1))) void*)g,
                                   (__attribute__((address_space(3))) void*)l,
                                   16, 0, 0);
}

struct HL { _Float16 h, l; };
__device__ __forceinline__ HL split_one(float a) {
  HL r;
  r.h = (_Float16)a;
  r.l = (_Float16)((a - (float)r.h) * 4096.0f);
  return r;
}

// ---------------------------------------------------------------------------
// X split: fp32 float4 -> hi/lo f16x4
// ---------------------------------------------------------------------------
__global__ void split_x(const float4* __restrict__ src, f16x4* __restrict__ dh,
                        f16x4* __restrict__ dl) {
  int i = blockIdx.x * 256 + threadIdx.x;  // 4194304 float4s
  float4 v = src[i];
  float a[4] = {v.x, v.y, v.z, v.w};
  f16x4 h, l;
#pragma unroll
  for (int j = 0; j < 4; j++) {
    HL r = split_one(a[j]);
    h[j] = r.h;
    l[j] = r.l;
  }
  dh[i] = h;
  dl[i] = l;
}

// ---------------------------------------------------------------------------
// all weight splits in one launch (scaled x256); W4 padded 160x256 -> 256x256
// ---------------------------------------------------------------------------
__global__ void split_weights(const float* __restrict__ W1, const float* __restrict__ W2,
                              const float* __restrict__ W3, const float* __restrict__ W4,
                              const float* __restrict__ b4,
                              f16x4* __restrict__ W1h, f16x4* __restrict__ W1l,
                              f16x4* __restrict__ W2h, f16x4* __restrict__ W2l,
                              f16x4* __restrict__ W3h, f16x4* __restrict__ W3l,
                              f16x4* __restrict__ W4h, f16x4* __restrict__ W4l,
                              float* __restrict__ b4p) {
  const int blk = blockIdx.x;
  const int tid = threadIdx.x;
  if (blk < 4736) {
    const float4* src;
    f16x4 *dh, *dl;
    int i;
    if (blk < 4096) {
      src = (const float4*)W1; dh = W1h; dl = W1l; i = blk * 256 + tid;
    } else if (blk < 4608) {
      src = (const float4*)W2; dh = W2h; dl = W2l; i = (blk - 4096) * 256 + tid;
    } else {
      src = (const float4*)W3; dh = W3h; dl = W3l; i = (blk - 4608) * 256 + tid;
    }
    float4 v = src[i];
    float a[4] = {v.x * 256.0f, v.y * 256.0f, v.z * 256.0f, v.w * 256.0f};
    f16x4 h, l;
#pragma unroll
    for (int j = 0; j < 4; j++) {
      HL r = split_one(a[j]);
      h[j] = r.h;
      l[j] = r.l;
    }
    dh[i] = h;
    dl[i] = l;
  } else if (blk < 4800) {
    int i = (blk - 4736) * 256 + tid;
    int i4 = i << 2;
    int row = i4 >> 8;
    f16x4 h, l;
#pragma unroll
    for (int j = 0; j < 4; j++) {
      float a = (row < 160) ? W4[i4 + j] * 256.0f : 0.0f;
      HL r = split_one(a);
      h[j] = r.h;
      l[j] = r.l;
    }
    W4h[i] = h;
    W4l[i] = l;
  } else {
    b4p[tid] = (tid < 160) ? b4[tid] : 0.0f;
  }
}

// ---------------------------------------------------------------------------
// R5 fused GEMM (G2-4): fp16x2 split-precision, double-buffered, fused epilogue.
// C[M,N] = A[M,K]*B[N,K]^T (+bias, relu). Tile TM x TN, 256 threads = 4 waves
// (2x2), wave tile (TM/2)x(TN/2) of 16x16x32 MFMAs. One barrier per K32 step.
// SWZ=1 (G2, 512 blocks 1-D): XCD decode y=xcd*8+(slot>>3), x=slot&7 so the
// 8 x-blocks sharing one A-panel run on one XCD. SWZ=0: plain 2-D launch.
// ---------------------------------------------------------------------------
template <int TM, int TN, int N, int K, bool RELU, bool SPLIT_OUT, int SWZ>
__global__ void __launch_bounds__(256, 2)
gemm_fused(const _Float16* __restrict__ Ah, const _Float16* __restrict__ Al,
           const _Float16* __restrict__ Bh, const _Float16* __restrict__ Bl,
           const float* __restrict__ bias,
           _Float16* __restrict__ Ch, _Float16* __restrict__ Cl,
           float* __restrict__ Cf) {
  constexpr int AM = TM / 32;
  constexpr int BN = TN / 32;
  constexpr int AU = TM / 8;
  constexpr int TU = (TM + TN) / 8;
  constexpr int UPW = TU / 4;
  constexpr int NK = K / 32;

  __shared__ __align__(16) _Float16 s[2][(TM + TN) * 64];

  const int tid = threadIdx.x;
  const int lane = tid & 63;
  const int w = tid >> 6;
  const int wm = w >> 1, wn = w & 1;

  int bx, by;
  if (SWZ == 1) {
    const int f = blockIdx.x;        // 512 blocks 1-D
    const int xcd = f & 7;
    const int slot = f >> 3;
    by = xcd * 8 + (slot >> 3);      // 0..63
    bx = slot & 7;                   // 0..7
  } else {
    bx = blockIdx.x;
    by = blockIdx.y;
  }
  const int m0 = by * TM;
  const int n0 = bx * TN;

  const int srow = lane >> 2;
  const int sk8 = (((lane & 3) - (lane >> 3)) & 3) * 8;

  const _Float16* gb[UPW];
  int lo[UPW];
#pragma unroll
  for (int i = 0; i < UPW; ++i) {
    const int u = w * UPW + i;
    if (u < AU) {
      const int g = u >> 1, hl = u & 1;
      gb[i] = (hl ? Al : Ah) + (size_t)(m0 + g * 16 + srow) * K + sk8;
    } else {
      const int ub = u - AU;
      const int g = ub >> 1, hl = ub & 1;
      gb[i] = (hl ? Bl : Bh) + (size_t)(n0 + g * 16 + srow) * K + sk8;
    }
    lo[i] = u * 512;
  }

  const int fr = lane & 15;
  const int fq = lane >> 4;
  const int fslot8 = (4 * fr + ((fq + (fr >> 1)) & 3)) * 8;

  f32x4 acc1[AM][BN], acc2[AM][BN];
#pragma unroll
  for (int i = 0; i < AM; i++)
#pragma unroll
    for (int j = 0; j < BN; j++) {
      acc1[i][j] = 0.0f;
      acc2[i][j] = 0.0f;
    }

#pragma unroll
  for (int i = 0; i < UPW; ++i) load16_lds(gb[i], &s[0][lo[i]]);

  for (int kt = 0; kt < NK; ++kt) {
    const int cur = kt & 1;
    __syncthreads();

    if (kt + 1 < NK) {
      const int kofs = (kt + 1) * 32;
#pragma unroll
      for (int i = 0; i < UPW; ++i) load16_lds(gb[i] + kofs, &s[cur ^ 1][lo[i]]);
    }

    f16x8 fAh[AM], fAl[AM], fBh[BN], fBl[BN];
#pragma unroll
    for (int im = 0; im < AM; ++im) {
      const int g = wm * AM + im;
      fAh[im] = *(const f16x8*)(&s[cur][(g * 2 + 0) * 512 + fslot8]);
      fAl[im] = *(const f16x8*)(&s[cur][(g * 2 + 1) * 512 + fslot8]);
    }
#pragma unroll
    for (int in = 0; in < BN; ++in) {
      const int g = wn * BN + in;
      fBh[in] = *(const f16x8*)(&s[cur][TM * 64 + (g * 2 + 0) * 512 + fslot8]);
      fBl[in] = *(const f16x8*)(&s[cur][TM * 64 + (g * 2 + 1) * 512 + fslot8]);
    }
#pragma unroll
    for (int im = 0; im < AM; ++im) {
#pragma unroll
      for (int in = 0; in < BN; ++in) {
        acc1[im][in] = __builtin_amdgcn_mfma_f32_16x16x32_f16(fAh[im], fBh[in], acc1[im][in], 0, 0, 0);
        acc2[im][in] = __builtin_amdgcn_mfma_f32_16x16x32_f16(fAh[im], fBl[in], acc2[im][in], 0, 0, 0);
        acc2[im][in] = __builtin_amdgcn_mfma_f32_16x16x32_f16(fAl[im], fBh[in], acc2[im][in], 0, 0, 0);
      }
    }
  }

  const int quad = lane >> 4;
#pragma unroll
  for (int in = 0; in < BN; ++in) {
    const int n = n0 + wn * (TN / 2) + in * 16 + fr;
    const float bv = bias[n];
#pragma unroll
    for (int im = 0; im < AM; ++im) {
#pragma unroll
      for (int r = 0; r < 4; ++r) {
        const int m = m0 + wm * (TM / 2) + im * 16 + quad * 4 + r;
        float c = (acc1[im][in][r] + acc2[im][in][r] * (1.0f / 4096.0f)) * (1.0f / 256.0f) + bv;
        if (RELU) c = fmaxf(c, 0.0f);
        const size_t off = (size_t)m * N + n;
        if (SPLIT_OUT) {
          HL rr = split_one(c);
          Ch[off] = rr.h;
          Cl[off] = rr.l;
        } else {
          Cf[off] = c;
        }
      }
    }
  }
}

// ---------------------------------------------------------------------------
// G1 split-K partial GEMM (R9 structure) + XCD swizzle: 1-D launch of 256
// blocks; decode xcd=f&7 -> bx=xcd>>1 (0..3), bz=xcd&1 (0..1), by=f>>3 (0..31).
// All 32 y-blocks of one (bx,bz) B-panel (2MB) share one XCD's L2.
// GY = number of y-tiles (M/TM) for the partial-output offset.
// ---------------------------------------------------------------------------
template <int TM, int TN, int N, int K, int KSPLIT, int GY>
__global__ void __launch_bounds__(256, 1)
gemm_part(const _Float16* __restrict__ Ah, const _Float16* __restrict__ Al,
          const _Float16* __restrict__ Bh, const _Float16* __restrict__ Bl,
          float* __restrict__ Cp) {
  constexpr int AM = TM / 32;
  constexpr int BN = TN / 32;
  constexpr int AU = TM / 8;
  constexpr int TU = (TM + TN) / 8;
  constexpr int UPW = TU / 4;
  constexpr int NK = K / KSPLIT / 32;

  __shared__ __align__(16) _Float16 s[2][(TM + TN) * 64];

  const int tid = threadIdx.x;
  const int lane = tid & 63;
  const int w = tid >> 6;
  const int wm = w >> 1, wn = w & 1;

  const int f = blockIdx.x;       // 256 blocks 1-D
  const int xcd = f & 7;
  const int bx = xcd >> 1;        // 0..3
  const int bz = xcd & 1;         // 0..1
  const int by = f >> 3;          // 0..31

  const int m0 = by * TM;
  const int n0 = bx * TN;
  const int kb = bz * (K / KSPLIT);

  const int srow = lane >> 2;
  const int sk8 = (((lane & 3) - (lane >> 3)) & 3) * 8;

  const _Float16* gb[UPW];
  int lo[UPW];
#pragma unroll
  for (int i = 0; i < UPW; ++i) {
    const int u = w * UPW + i;
    if (u < AU) {
      const int g = u >> 1, hl = u & 1;
      gb[i] = (hl ? Al : Ah) + (size_t)(m0 + g * 16 + srow) * K + kb + sk8;
    } else {
      const int ub = u - AU;
      const int g = ub >> 1, hl = ub & 1;
      gb[i] = (hl ? Bl : Bh) + (size_t)(n0 + g * 16 + srow) * K + kb + sk8;
    }
    lo[i] = u * 512;
  }

  const int fr = lane & 15;
  const int fq = lane >> 4;
  const int fslot8 = (4 * fr + ((fq + (fr >> 1)) & 3)) * 8;

  f32x4 acc1[AM][BN], acc2[AM][BN];
#pragma unroll
  for (int i = 0; i < AM; i++)
#pragma unroll
    for (int j = 0; j < BN; j++) {
      acc1[i][j] = 0.0f;
      acc2[i][j] = 0.0f;
    }

#pragma unroll
  for (int i = 0; i < UPW; ++i) load16_lds(gb[i], &s[0][lo[i]]);

  for (int kt = 0; kt < NK; ++kt) {
    const int cur = kt & 1;
    __syncthreads();

    if (kt + 1 < NK) {
      const int kofs = (kt + 1) * 32;
#pragma unroll
      for (int i = 0; i < UPW; ++i) load16_lds(gb[i] + kofs, &s[cur ^ 1][lo[i]]);
    }

    f16x8 fAh[AM], fAl[AM], fBh[BN], fBl[BN];
#pragma unroll
    for (int im = 0; im < AM; ++im) {
      const int g = wm * AM + im;
      fAh[im] = *(const f16x8*)(&s[cur][(g * 2 + 0) * 512 + fslot8]);
      fAl[im] = *(const f16x8*)(&s[cur][(g * 2 + 1) * 512 + fslot8]);
    }
#pragma unroll
    for (int in = 0; in < BN; ++in) {
      const int g = wn * BN + in;
      fBh[in] = *(const f16x8*)(&s[cur][TM * 64 + (g * 2 + 0) * 512 + fslot8]);
      fBl[in] = *(const f16x8*)(&s[cur][TM * 64 + (g * 2 + 1) * 512 + fslot8]);
    }
#pragma unroll
    for (int im = 0; im < AM; ++im) {
#pragma unroll
      for (int in = 0; in < BN; ++in) {
        acc1[im][in] = __builtin_amdgcn_mfma_f32_16x16x32_f16(fAh[im], fBh[in], acc1[im][in], 0, 0, 0);
        acc2[im][in] = __builtin_amdgcn_mfma_f32_16x16x32_f16(fAh[im], fBl[in], acc2[im][in], 0, 0, 0);
        acc2[im][in] = __builtin_amdgcn_mfma_f32_16x16x32_f16(fAl[im], fBh[in], acc2[im][in], 0, 0, 0);
      }
    }
  }

  const int quad = lane >> 4;
  float* Cz = Cp + (size_t)bz * ((size_t)GY * TM) * N;
#pragma unroll
  for (int in = 0; in < BN; ++in) {
    const int n = n0 + wn * (TN / 2) + in * 16 + fr;
#pragma unroll
    for (int im = 0; im < AM; ++im) {
#pragma unroll
      for (int r = 0; r < 4; ++r) {
        const int m = m0 + wm * (TM / 2) + im * 16 + quad * 4 + r;
        Cz[(size_t)m * N + n] = acc1[im][in][r] + acc2[im][in][r] * (1.0f / 4096.0f);
      }
    }
  }
}

// ---------------------------------------------------------------------------
// combine: c = (p0 + p1) * (1/256) + bias[n]; relu; split f16 out. (R8-verified)
// ---------------------------------------------------------------------------
__global__ void __launch_bounds__(256)
combine1(const float* __restrict__ Cp, const float* __restrict__ bias, int N,
         size_t halfN, _Float16* __restrict__ Ch, _Float16* __restrict__ Cl) {
  const size_t i4 = ((size_t)blockIdx.x * 256 + threadIdx.x) * 4;
  float4 p0 = *(const float4*)(Cp + i4);
  float4 p1 = *(const float4*)(Cp + halfN + i4);
  float4 bv = *(const float4*)(bias + (i4 % (size_t)N));
  float c[4] = {(p0.x + p1.x) * (1.0f / 256.0f) + bv.x,
                (p0.y + p1.y) * (1.0f / 256.0f) + bv.y,
                (p0.z + p1.z) * (1.0f / 256.0f) + bv.z,
                (p0.w + p1.w) * (1.0f / 256.0f) + bv.w};
  f16x4 h, l;
#pragma unroll
  for (int j = 0; j < 4; j++) {
    c[j] = fmaxf(c[j], 0.0f);
    HL r = split_one(c[j]);
    h[j] = r.h;
    l[j] = r.l;
  }
  *(f16x4*)(Ch + i4) = h;
  *(f16x4*)(Cl + i4) = l;
}

// ---------------------------------------------------------------------------
// Gabor synthesis: one block per batch; thread owns 8 contiguous t samples,
// per-wavelet wave-uniform 5-sigma window skip.
// ---------------------------------------------------------------------------
__global__ void __launch_bounds__(256)
synth(const float* __restrict__ P, float* __restrict__ out) {
  __shared__ float sA[NWAV], sT0[NWAV], sF[NWAV], sC[NWAV], sPh[NWAV], sSg[NWAV];
  const int b = blockIdx.x;
  const int tid = threadIdx.x;
  if (tid < NWAV) {
    const float* q = P + (size_t)b * 256 + tid * 5;
    const float L2E = 1.44269504088896340736f;
    float A = q[0], p1 = q[1], p2 = q[2], p3 = q[3], p4 = q[4];
    float s1 = 1.0f / (1.0f + exp2f(-p1 * L2E));
    float s2 = 1.0f / (1.0f + exp2f(-p2 * L2E));
    float s3 = 1.0f / (1.0f + exp2f(-p3 * L2E));
    float sg = s3 * 200.0f + 2.0f;
    sA[tid] = A;
    sT0[tid] = s1 * 2048.0f;
    sF[tid] = s2 * 0.5f;
    sC[tid] = -L2E / (2.0f * sg * sg);
    sPh[tid] = p4 * 0.15915494309189535f;
    sSg[tid] = sg;
  }
  __syncthreads();

  const float t0f = (float)(tid * 8);
  const int wlo = (tid & ~63) * 8;
  float acc[8];
#pragma unroll
  for (int i = 0; i < 8; i++) acc[i] = 0.0f;

  for (int wv = 0; wv < NWAV; wv++) {
    const float t0 = sT0[wv], sg = sSg[wv];
    if (t0 + 5.0f * sg < (float)wlo || t0 - 5.0f * sg > (float)(wlo + 511)) continue;
    const float A = sA[wv], fr = sF[wv], cn = sC[wv], ph = sPh[wv];
#pragma unroll
    for (int i = 0; i < 8; i++) {
      float dt = (t0f + (float)i) - t0;
      float e = exp2f(dt * dt * cn);
      float r = fr * dt + ph;
      r -= floorf(r);
      float cs = __builtin_amdgcn_cosf(r);
      acc[i] += A * e * cs;
    }
  }

  float* o = out + (size_t)b * (2 * SIGNAL_LEN) + tid * 8;
  float4 v0 = make_float4(acc[0], acc[1], acc[2], acc[3]);
  float4 v1 = make_float4(acc[4], acc[5], acc[6], acc[7]);
  *(float4*)(o) = v0;
  *(float4*)(o + 4) = v1;
  *(float4*)(o + SIGNAL_LEN) = v0;
  *(float4*)(o + SIGNAL_LEN + 4) = v1;
}

// ---------------------------------------------------------------------------
extern "C" void kernel_launch(void* const* d_in, const int* in_sizes, int n_in,
                              void* d_out, int out_size, void* d_ws, size_t ws_size,
                              hipStream_t stream) {
  (void)in_sizes; (void)n_in; (void)out_size; (void)ws_size;
  const float* X  = (const float*)d_in[0];
  const float* W1 = (const float*)d_in[1];
  const float* b1 = (const float*)d_in[2];
  const float* W2 = (const float*)d_in[3];
  const float* b2 = (const float*)d_in[4];
  const float* W3 = (const float*)d_in[5];
  const float* b3 = (const float*)d_in[6];
  const float* W4 = (const float*)d_in[7];
  const float* b4 = (const float*)d_in[8];
  float* out = (float*)d_out;

  char* p = (char*)d_ws;
  auto take = [&](size_t bytes) -> char* {
    char* r = p;
    p += (bytes + 255) & ~(size_t)255;
    return r;
  };
  _Float16* Xh  = (_Float16*)take((size_t)4096 * 4096 * 2);
  _Float16* Xl  = (_Float16*)take((size_t)4096 * 4096 * 2);
  _Float16* W1h = (_Float16*)take((size_t)1024 * 4096 * 2);
  _Float16* W1l = (_Float16*)take((size_t)1024 * 4096 * 2);
  _Float16* H1h = (_Float16*)take((size_t)4096 * 1024 * 2);
  _Float16* H1l = (_Float16*)take((size_t)4096 * 1024 * 2);
  _Float16* W2h = (_Float16*)take((size_t)512 * 1024 * 2);
  _Float16* W2l = (_Float16*)take((size_t)512 * 1024 * 2);
  _Float16* H2h = (_Float16*)take((size_t)4096 * 512 * 2);
  _Float16* H2l = (_Float16*)take((size_t)4096 * 512 * 2);
  _Float16* W3h = (_Float16*)take((size_t)256 * 512 * 2);
  _Float16* W3l = (_Float16*)take((size_t)256 * 512 * 2);
  _Float16* H3h = (_Float16*)take((size_t)4096 * 256 * 2);
  _Float16* H3l = (_Float16*)take((size_t)4096 * 256 * 2);
  _Float16* W4h = (_Float16*)take((size_t)256 * 256 * 2);
  _Float16* W4l = (_Float16*)take((size_t)256 * 256 * 2);
  float*    b4p = (float*)take(256 * 4);
  float*    Pp  = (float*)take((size_t)4096 * 256 * 4);
  float*    Cp  = (float*)take((size_t)2 * 4096 * 1024 * 4);  // G1 split-K partials

  split_x<<<16384, 256, 0, stream>>>((const float4*)X, (f16x4*)Xh, (f16x4*)Xl);
  split_weights<<<4801, 256, 0, stream>>>(W1, W2, W3, W4, b4,
                                          (f16x4*)W1h, (f16x4*)W1l, (f16x4*)W2h, (f16x4*)W2l,
                                          (f16x4*)W3h, (f16x4*)W3l, (f16x4*)W4h, (f16x4*)W4l, b4p);

  // G1: 128x256, splitK=2, 256 blocks 1-D with XCD decode (R9 structure)
  gemm_part<128, 256, 1024, 4096, 2, 32><<<256, 256, 0, stream>>>(
      Xh, Xl, W1h, W1l, Cp);
  combine1<<<4096, 256, 0, stream>>>(Cp, b1, 1024, (size_t)4096 * 1024, H1h, H1l);

  // G2: 64x64, 512 blocks 1-D with XCD decode (same-y co-located)
  gemm_fused<64, 64, 512, 1024, true, true, 1><<<512, 256, 0, stream>>>(
      H1h, H1l, W2h, W2l, b2, H2h, H2l, nullptr);
  // G3/G4: R11-exact 2-D launches
  gemm_fused<32, 64, 256, 512, true, true, 0><<<dim3(4, 128), 256, 0, stream>>>(
      H2h, H2l, W3h, W3l, b3, H3h, H3l, nullptr);
  gemm_fused<32, 64, 256, 256, false, false, 0><<<dim3(4, 128), 256, 0, stream>>>(
      H3h, H3l, W4h, W4l, b4p, nullptr, nullptr, Pp);

  synth<<<4096, 256, 0, stream>>>(Pp, out);
}

// Round 10
// 356.482 us; speedup vs baseline: 1.2854x; 1.0911x over previous
//
#include <hip/hip_runtime.h>

// GaborAutoencoder on MI355X (gfx950)
// split fp32 -> fp16 (hi, lo*4096) -> 3-pass split-precision MFMA GEMMs -> Gabor synth.
// R15: G1/G2-4/combine1 = R14-exact (banked 388.9us; G1 at the m97-structure
//      MFMA ceiling: 3x-MFMA split work = 846TF ~ the 874-912 documented limit).
//      New: (1) synth rewritten with exact per-sample recurrences -- exp2 of the
//      quadratic via g*=m, m*=q (q=exp2(2cn) per-wavelet) and cos via complex
//      rotation by (cw,sw) -- 16 trans/(thread,wavelet) -> 4; m0 exponent
//      clamped to 120 so g0-underflow never makes 0*inf NaN; A folded into g0.
//      (2) split_x + split_weights fused into one launch (block-range dispatch).
//      Purpose: locate the ~100us unaccounted between sum-of-parts and total;
//      synth is the prime suspect if v_exp/v_cos are quarter-rate.

#define SIGNAL_LEN 2048
#define NWAV 32

typedef _Float16 f16x8 __attribute__((ext_vector_type(8)));
typedef _Float16 f16x4 __attribute__((ext_vector_type(4)));
typedef float    f32x4 __attribute__((ext_vector_type(4)));

__device__ __forceinline__ void load16_lds(const _Float16* g, _Float16* l) {
  __builtin_amdgcn_global_load_lds((const __attribute__((address_space(1))) void*)g,
                                   (__attribute__((address_space(3))) void*)l,
                                   16, 0, 0);
}

struct HL { _Float16 h, l; };
__device__ __forceinline__ HL split_one(float a) {
  HL r;
  r.h = (_Float16)a;
  r.l = (_Float16)((a - (float)r.h) * 4096.0f);
  return r;
}

// ---------------------------------------------------------------------------
// fused input split: blocks [0,16384) = X (fp32 float4 -> hi/lo f16x4);
// blocks [16384, 21185) = weights (scaled x256; W4 padded 160x256 -> 256x256).
// ---------------------------------------------------------------------------
__global__ void split_all(const float4* __restrict__ Xsrc, f16x4* __restrict__ Xh,
                          f16x4* __restrict__ Xl,
                          const float* __restrict__ W1, const float* __restrict__ W2,
                          const float* __restrict__ W3, const float* __restrict__ W4,
                          const float* __restrict__ b4,
                          f16x4* __restrict__ W1h, f16x4* __restrict__ W1l,
                          f16x4* __restrict__ W2h, f16x4* __restrict__ W2l,
                          f16x4* __restrict__ W3h, f16x4* __restrict__ W3l,
                          f16x4* __restrict__ W4h, f16x4* __restrict__ W4l,
                          float* __restrict__ b4p) {
  const int tid = threadIdx.x;
  if (blockIdx.x < 16384) {
    int i = blockIdx.x * 256 + tid;  // 4194304 float4s
    float4 v = Xsrc[i];
    float a[4] = {v.x, v.y, v.z, v.w};
    f16x4 h, l;
#pragma unroll
    for (int j = 0; j < 4; j++) {
      HL r = split_one(a[j]);
      h[j] = r.h;
      l[j] = r.l;
    }
    Xh[i] = h;
    Xl[i] = l;
    return;
  }
  const int blk = blockIdx.x - 16384;
  if (blk < 4736) {
    const float4* src;
    f16x4 *dh, *dl;
    int i;
    if (blk < 4096) {
      src = (const float4*)W1; dh = W1h; dl = W1l; i = blk * 256 + tid;
    } else if (blk < 4608) {
      src = (const float4*)W2; dh = W2h; dl = W2l; i = (blk - 4096) * 256 + tid;
    } else {
      src = (const float4*)W3; dh = W3h; dl = W3l; i = (blk - 4608) * 256 + tid;
    }
    float4 v = src[i];
    float a[4] = {v.x * 256.0f, v.y * 256.0f, v.z * 256.0f, v.w * 256.0f};
    f16x4 h, l;
#pragma unroll
    for (int j = 0; j < 4; j++) {
      HL r = split_one(a[j]);
      h[j] = r.h;
      l[j] = r.l;
    }
    dh[i] = h;
    dl[i] = l;
  } else if (blk < 4800) {
    int i = (blk - 4736) * 256 + tid;
    int i4 = i << 2;
    int row = i4 >> 8;
    f16x4 h, l;
#pragma unroll
    for (int j = 0; j < 4; j++) {
      float a = (row < 160) ? W4[i4 + j] * 256.0f : 0.0f;
      HL r = split_one(a);
      h[j] = r.h;
      l[j] = r.l;
    }
    W4h[i] = h;
    W4l[i] = l;
  } else {
    b4p[tid] = (tid < 160) ? b4[tid] : 0.0f;
  }
}

// ---------------------------------------------------------------------------
// R5 fused GEMM (G2-4): fp16x2 split-precision, double-buffered, fused epilogue.
// SWZ=1 (G2, 512 blocks 1-D): XCD decode y=xcd*8+(slot>>3), x=slot&7.
// ---------------------------------------------------------------------------
template <int TM, int TN, int N, int K, bool RELU, bool SPLIT_OUT, int SWZ>
__global__ void __launch_bounds__(256, 2)
gemm_fused(const _Float16* __restrict__ Ah, const _Float16* __restrict__ Al,
           const _Float16* __restrict__ Bh, const _Float16* __restrict__ Bl,
           const float* __restrict__ bias,
           _Float16* __restrict__ Ch, _Float16* __restrict__ Cl,
           float* __restrict__ Cf) {
  constexpr int AM = TM / 32;
  constexpr int BN = TN / 32;
  constexpr int AU = TM / 8;
  constexpr int TU = (TM + TN) / 8;
  constexpr int UPW = TU / 4;
  constexpr int NK = K / 32;

  __shared__ __align__(16) _Float16 s[2][(TM + TN) * 64];

  const int tid = threadIdx.x;
  const int lane = tid & 63;
  const int w = tid >> 6;
  const int wm = w >> 1, wn = w & 1;

  int bx, by;
  if (SWZ == 1) {
    const int f = blockIdx.x;        // 512 blocks 1-D
    const int xcd = f & 7;
    const int slot = f >> 3;
    by = xcd * 8 + (slot >> 3);      // 0..63
    bx = slot & 7;                   // 0..7
  } else {
    bx = blockIdx.x;
    by = blockIdx.y;
  }
  const int m0 = by * TM;
  const int n0 = bx * TN;

  const int srow = lane >> 2;
  const int sk8 = (((lane & 3) - (lane >> 3)) & 3) * 8;

  const _Float16* gb[UPW];
  int lo[UPW];
#pragma unroll
  for (int i = 0; i < UPW; ++i) {
    const int u = w * UPW + i;
    if (u < AU) {
      const int g = u >> 1, hl = u & 1;
      gb[i] = (hl ? Al : Ah) + (size_t)(m0 + g * 16 + srow) * K + sk8;
    } else {
      const int ub = u - AU;
      const int g = ub >> 1, hl = ub & 1;
      gb[i] = (hl ? Bl : Bh) + (size_t)(n0 + g * 16 + srow) * K + sk8;
    }
    lo[i] = u * 512;
  }

  const int fr = lane & 15;
  const int fq = lane >> 4;
  const int fslot8 = (4 * fr + ((fq + (fr >> 1)) & 3)) * 8;

  f32x4 acc1[AM][BN], acc2[AM][BN];
#pragma unroll
  for (int i = 0; i < AM; i++)
#pragma unroll
    for (int j = 0; j < BN; j++) {
      acc1[i][j] = 0.0f;
      acc2[i][j] = 0.0f;
    }

#pragma unroll
  for (int i = 0; i < UPW; ++i) load16_lds(gb[i], &s[0][lo[i]]);

  for (int kt = 0; kt < NK; ++kt) {
    const int cur = kt & 1;
    __syncthreads();

    if (kt + 1 < NK) {
      const int kofs = (kt + 1) * 32;
#pragma unroll
      for (int i = 0; i < UPW; ++i) load16_lds(gb[i] + kofs, &s[cur ^ 1][lo[i]]);
    }

    f16x8 fAh[AM], fAl[AM], fBh[BN], fBl[BN];
#pragma unroll
    for (int im = 0; im < AM; ++im) {
      const int g = wm * AM + im;
      fAh[im] = *(const f16x8*)(&s[cur][(g * 2 + 0) * 512 + fslot8]);
      fAl[im] = *(const f16x8*)(&s[cur][(g * 2 + 1) * 512 + fslot8]);
    }
#pragma unroll
    for (int in = 0; in < BN; ++in) {
      const int g = wn * BN + in;
      fBh[in] = *(const f16x8*)(&s[cur][TM * 64 + (g * 2 + 0) * 512 + fslot8]);
      fBl[in] = *(const f16x8*)(&s[cur][TM * 64 + (g * 2 + 1) * 512 + fslot8]);
    }
#pragma unroll
    for (int im = 0; im < AM; ++im) {
#pragma unroll
      for (int in = 0; in < BN; ++in) {
        acc1[im][in] = __builtin_amdgcn_mfma_f32_16x16x32_f16(fAh[im], fBh[in], acc1[im][in], 0, 0, 0);
        acc2[im][in] = __builtin_amdgcn_mfma_f32_16x16x32_f16(fAh[im], fBl[in], acc2[im][in], 0, 0, 0);
        acc2[im][in] = __builtin_amdgcn_mfma_f32_16x16x32_f16(fAl[im], fBh[in], acc2[im][in], 0, 0, 0);
      }
    }
  }

  const int quad = lane >> 4;
#pragma unroll
  for (int in = 0; in < BN; ++in) {
    const int n = n0 + wn * (TN / 2) + in * 16 + fr;
    const float bv = bias[n];
#pragma unroll
    for (int im = 0; im < AM; ++im) {
#pragma unroll
      for (int r = 0; r < 4; ++r) {
        const int m = m0 + wm * (TM / 2) + im * 16 + quad * 4 + r;
        float c = (acc1[im][in][r] + acc2[im][in][r] * (1.0f / 4096.0f)) * (1.0f / 256.0f) + bv;
        if (RELU) c = fmaxf(c, 0.0f);
        const size_t off = (size_t)m * N + n;
        if (SPLIT_OUT) {
          HL rr = split_one(c);
          Ch[off] = rr.h;
          Cl[off] = rr.l;
        } else {
          Cf[off] = c;
        }
      }
    }
  }
}

// ---------------------------------------------------------------------------
// G1 split-K partial GEMM (R9 structure) + XCD swizzle (R14-verified):
// 1-D 256 blocks; xcd=f&7 -> bx=xcd>>1, bz=xcd&1, by=f>>3.
// ---------------------------------------------------------------------------
template <int TM, int TN, int N, int K, int KSPLIT, int GY>
__global__ void __launch_bounds__(256, 1)
gemm_part(const _Float16* __restrict__ Ah, const _Float16* __restrict__ Al,
          const _Float16* __restrict__ Bh, const _Float16* __restrict__ Bl,
          float* __restrict__ Cp) {
  constexpr int AM = TM / 32;
  constexpr int BN = TN / 32;
  constexpr int AU = TM / 8;
  constexpr int TU = (TM + TN) / 8;
  constexpr int UPW = TU / 4;
  constexpr int NK = K / KSPLIT / 32;

  __shared__ __align__(16) _Float16 s[2][(TM + TN) * 64];

  const int tid = threadIdx.x;
  const int lane = tid & 63;
  const int w = tid >> 6;
  const int wm = w >> 1, wn = w & 1;

  const int f = blockIdx.x;       // 256 blocks 1-D
  const int xcd = f & 7;
  const int bx = xcd >> 1;        // 0..3
  const int bz = xcd & 1;         // 0..1
  const int by = f >> 3;          // 0..31

  const int m0 = by * TM;
  const int n0 = bx * TN;
  const int kb = bz * (K / KSPLIT);

  const int srow = lane >> 2;
  const int sk8 = (((lane & 3) - (lane >> 3)) & 3) * 8;

  const _Float16* gb[UPW];
  int lo[UPW];
#pragma unroll
  for (int i = 0; i < UPW; ++i) {
    const int u = w * UPW + i;
    if (u < AU) {
      const int g = u >> 1, hl = u & 1;
      gb[i] = (hl ? Al : Ah) + (size_t)(m0 + g * 16 + srow) * K + kb + sk8;
    } else {
      const int ub = u - AU;
      const int g = ub >> 1, hl = ub & 1;
      gb[i] = (hl ? Bl : Bh) + (size_t)(n0 + g * 16 + srow) * K + kb + sk8;
    }
    lo[i] = u * 512;
  }

  const int fr = lane & 15;
  const int fq = lane >> 4;
  const int fslot8 = (4 * fr + ((fq + (fr >> 1)) & 3)) * 8;

  f32x4 acc1[AM][BN], acc2[AM][BN];
#pragma unroll
  for (int i = 0; i < AM; i++)
#pragma unroll
    for (int j = 0; j < BN; j++) {
      acc1[i][j] = 0.0f;
      acc2[i][j] = 0.0f;
    }

#pragma unroll
  for (int i = 0; i < UPW; ++i) load16_lds(gb[i], &s[0][lo[i]]);

  for (int kt = 0; kt < NK; ++kt) {
    const int cur = kt & 1;
    __syncthreads();

    if (kt + 1 < NK) {
      const int kofs = (kt + 1) * 32;
#pragma unroll
      for (int i = 0; i < UPW; ++i) load16_lds(gb[i] + kofs, &s[cur ^ 1][lo[i]]);
    }

    f16x8 fAh[AM], fAl[AM], fBh[BN], fBl[BN];
#pragma unroll
    for (int im = 0; im < AM; ++im) {
      const int g = wm * AM + im;
      fAh[im] = *(const f16x8*)(&s[cur][(g * 2 + 0) * 512 + fslot8]);
      fAl[im] = *(const f16x8*)(&s[cur][(g * 2 + 1) * 512 + fslot8]);
    }
#pragma unroll
    for (int in = 0; in < BN; ++in) {
      const int g = wn * BN + in;
      fBh[in] = *(const f16x8*)(&s[cur][TM * 64 + (g * 2 + 0) * 512 + fslot8]);
      fBl[in] = *(const f16x8*)(&s[cur][TM * 64 + (g * 2 + 1) * 512 + fslot8]);
    }
#pragma unroll
    for (int im = 0; im < AM; ++im) {
#pragma unroll
      for (int in = 0; in < BN; ++in) {
        acc1[im][in] = __builtin_amdgcn_mfma_f32_16x16x32_f16(fAh[im], fBh[in], acc1[im][in], 0, 0, 0);
        acc2[im][in] = __builtin_amdgcn_mfma_f32_16x16x32_f16(fAh[im], fBl[in], acc2[im][in], 0, 0, 0);
        acc2[im][in] = __builtin_amdgcn_mfma_f32_16x16x32_f16(fAl[im], fBh[in], acc2[im][in], 0, 0, 0);
      }
    }
  }

  const int quad = lane >> 4;
  float* Cz = Cp + (size_t)bz * ((size_t)GY * TM) * N;
#pragma unroll
  for (int in = 0; in < BN; ++in) {
    const int n = n0 + wn * (TN / 2) + in * 16 + fr;
#pragma unroll
    for (int im = 0; im < AM; ++im) {
#pragma unroll
      for (int r = 0; r < 4; ++r) {
        const int m = m0 + wm * (TM / 2) + im * 16 + quad * 4 + r;
        Cz[(size_t)m * N + n] = acc1[im][in][r] + acc2[im][in][r] * (1.0f / 4096.0f);
      }
    }
  }
}

// ---------------------------------------------------------------------------
// combine: c = (p0 + p1) * (1/256) + bias[n]; relu; split f16 out. (R8-verified)
// ---------------------------------------------------------------------------
__global__ void __launch_bounds__(256)
combine1(const float* __restrict__ Cp, const float* __restrict__ bias, int N,
         size_t halfN, _Float16* __restrict__ Ch, _Float16* __restrict__ Cl) {
  const size_t i4 = ((size_t)blockIdx.x * 256 + threadIdx.x) * 4;
  float4 p0 = *(const float4*)(Cp + i4);
  float4 p1 = *(const float4*)(Cp + halfN + i4);
  float4 bv = *(const float4*)(bias + (i4 % (size_t)N));
  float c[4] = {(p0.x + p1.x) * (1.0f / 256.0f) + bv.x,
                (p0.y + p1.y) * (1.0f / 256.0f) + bv.y,
                (p0.z + p1.z) * (1.0f / 256.0f) + bv.z,
                (p0.w + p1.w) * (1.0f / 256.0f) + bv.w};
  f16x4 h, l;
#pragma unroll
  for (int j = 0; j < 4; j++) {
    c[j] = fmaxf(c[j], 0.0f);
    HL r = split_one(c[j]);
    h[j] = r.h;
    l[j] = r.l;
  }
  *(f16x4*)(Ch + i4) = h;
  *(f16x4*)(Cl + i4) = l;
}

// ---------------------------------------------------------------------------
// Gabor synthesis with per-sample recurrences (R15):
//  exp2(cn*dt^2): g *= m, m *= q where q = exp2(2cn) (per-wavelet, LDS).
//  cos(2*pi*r):   complex rotation by (cw, sw) = (cos, sin) of 2*pi*f.
// Per (thread, wavelet): 4 trans setup (was 16) + 7 VALU/sample.
// m0 exponent clamped to 120: if g0 underflowed (negligible window) the
// products stay 0 instead of 0*inf=NaN. A folded into g0.
// ---------------------------------------------------------------------------
__global__ void __launch_bounds__(256)
synth(const float* __restrict__ P, float* __restrict__ out) {
  __shared__ float sA[NWAV], sT0[NWAV], sF[NWAV], sC[NWAV], sPh[NWAV], sSg[NWAV];
  __shared__ float sQ[NWAV], sCw[NWAV], sSw[NWAV];
  const int b = blockIdx.x;
  const int tid = threadIdx.x;
  if (tid < NWAV) {
    const float* qp = P + (size_t)b * 256 + tid * 5;
    const float L2E = 1.44269504088896340736f;
    float A = qp[0], p1 = qp[1], p2 = qp[2], p3 = qp[3], p4 = qp[4];
    float s1 = 1.0f / (1.0f + exp2f(-p1 * L2E));
    float s2 = 1.0f / (1.0f + exp2f(-p2 * L2E));
    float s3 = 1.0f / (1.0f + exp2f(-p3 * L2E));
    float sg = s3 * 200.0f + 2.0f;
    float fv = s2 * 0.5f;                    // revolutions per sample
    float cn = -L2E / (2.0f * sg * sg);
    sA[tid] = A;
    sT0[tid] = s1 * 2048.0f;
    sF[tid] = fv;
    sC[tid] = cn;
    sPh[tid] = p4 * 0.15915494309189535f;
    sSg[tid] = sg;
    sQ[tid] = exp2f(2.0f * cn);
    sCw[tid] = __builtin_amdgcn_cosf(fv);    // cos(2*pi*f), f in [0,0.5]
    float fx = fv - 0.25f;
    fx -= floorf(fx);
    sSw[tid] = __builtin_amdgcn_cosf(fx);    // sin(2*pi*f)
  }
  __syncthreads();

  const float t0f = (float)(tid * 8);
  const int wlo = (tid & ~63) * 8;
  float acc[8];
#pragma unroll
  for (int i = 0; i < 8; i++) acc[i] = 0.0f;

  for (int wv = 0; wv < NWAV; wv++) {
    const float t0 = sT0[wv], sg = sSg[wv];
    if (t0 + 5.0f * sg < (float)wlo || t0 - 5.0f * sg > (float)(wlo + 511)) continue;
    const float A = sA[wv], fv = sF[wv], cn = sC[wv], ph = sPh[wv];
    const float q = sQ[wv], cw = sCw[wv], sw = sSw[wv];

    const float dt0 = t0f - t0;
    float g = exp2f(dt0 * dt0 * cn) * A;                 // A*exp at sample 0
    float mf = fminf(cn * (2.0f * dt0 + 1.0f), 120.0f);  // clamp: no 0*inf
    float m = exp2f(mf);
    float r0 = fv * dt0 + ph;
    r0 -= floorf(r0);
    float c = __builtin_amdgcn_cosf(r0);
    float rs = r0 - 0.25f;
    rs -= floorf(rs);
    float s = __builtin_amdgcn_cosf(rs);                 // sin(2*pi*r0)

#pragma unroll
    for (int i = 0; i < 8; i++) {
      acc[i] = fmaf(g, c, acc[i]);
      float c2 = c * cw - s * sw;
      s = fmaf(c, sw, s * cw);
      c = c2;
      g *= m;
      m *= q;
    }
  }

  float* o = out + (size_t)b * (2 * SIGNAL_LEN) + tid * 8;
  float4 v0 = make_float4(acc[0], acc[1], acc[2], acc[3]);
  float4 v1 = make_float4(acc[4], acc[5], acc[6], acc[7]);
  *(float4*)(o) = v0;
  *(float4*)(o + 4) = v1;
  *(float4*)(o + SIGNAL_LEN) = v0;
  *(float4*)(o + SIGNAL_LEN + 4) = v1;
}

// ---------------------------------------------------------------------------
extern "C" void kernel_launch(void* const* d_in, const int* in_sizes, int n_in,
                              void* d_out, int out_size, void* d_ws, size_t ws_size,
                              hipStream_t stream) {
  (void)in_sizes; (void)n_in; (void)out_size; (void)ws_size;
  const float* X  = (const float*)d_in[0];
  const float* W1 = (const float*)d_in[1];
  const float* b1 = (const float*)d_in[2];
  const float* W2 = (const float*)d_in[3];
  const float* b2 = (const float*)d_in[4];
  const float* W3 = (const float*)d_in[5];
  const float* b3 = (const float*)d_in[6];
  const float* W4 = (const float*)d_in[7];
  const float* b4 = (const float*)d_in[8];
  float* out = (float*)d_out;

  char* p = (char*)d_ws;
  auto take = [&](size_t bytes) -> char* {
    char* r = p;
    p += (bytes + 255) & ~(size_t)255;
    return r;
  };
  _Float16* Xh  = (_Float16*)take((size_t)4096 * 4096 * 2);
  _Float16* Xl  = (_Float16*)take((size_t)4096 * 4096 * 2);
  _Float16* W1h = (_Float16*)take((size_t)1024 * 4096 * 2);
  _Float16* W1l = (_Float16*)take((size_t)1024 * 4096 * 2);
  _Float16* H1h = (_Float16*)take((size_t)4096 * 1024 * 2);
  _Float16* H1l = (_Float16*)take((size_t)4096 * 1024 * 2);
  _Float16* W2h = (_Float16*)take((size_t)512 * 1024 * 2);
  _Float16* W2l = (_Float16*)take((size_t)512 * 1024 * 2);
  _Float16* H2h = (_Float16*)take((size_t)4096 * 512 * 2);
  _Float16* H2l = (_Float16*)take((size_t)4096 * 512 * 2);
  _Float16* W3h = (_Float16*)take((size_t)256 * 512 * 2);
  _Float16* W3l = (_Float16*)take((size_t)256 * 512 * 2);
  _Float16* H3h = (_Float16*)take((size_t)4096 * 256 * 2);
  _Float16* H3l = (_Float16*)take((size_t)4096 * 256 * 2);
  _Float16* W4h = (_Float16*)take((size_t)256 * 256 * 2);
  _Float16* W4l = (_Float16*)take((size_t)256 * 256 * 2);
  float*    b4p = (float*)take(256 * 4);
  float*    Pp  = (float*)take((size_t)4096 * 256 * 4);
  float*    Cp  = (float*)take((size_t)2 * 4096 * 1024 * 4);  // G1 split-K partials

  split_all<<<21185, 256, 0, stream>>>((const float4*)X, (f16x4*)Xh, (f16x4*)Xl,
                                       W1, W2, W3, W4, b4,
                                       (f16x4*)W1h, (f16x4*)W1l, (f16x4*)W2h, (f16x4*)W2l,
                                       (f16x4*)W3h, (f16x4*)W3l, (f16x4*)W4h, (f16x4*)W4l, b4p);

  // G1: 128x256, splitK=2, 256 blocks 1-D with XCD decode (R14-exact)
  gemm_part<128, 256, 1024, 4096, 2, 32><<<256, 256, 0, stream>>>(
      Xh, Xl, W1h, W1l, Cp);
  combine1<<<4096, 256, 0, stream>>>(Cp, b1, 1024, (size_t)4096 * 1024, H1h, H1l);

  // G2: 64x64, 512 blocks 1-D with XCD decode (R14-exact)
  gemm_fused<64, 64, 512, 1024, true, true, 1><<<512, 256, 0, stream>>>(
      H1h, H1l, W2h, W2l, b2, H2h, H2l, nullptr);
  // G3/G4: R11-exact 2-D launches
  gemm_fused<32, 64, 256, 512, true, true, 0><<<dim3(4, 128), 256, 0, stream>>>(
      H2h, H2l, W3h, W3l, b3, H3h, H3l, nullptr);
  gemm_fused<32, 64, 256, 256, false, false, 0><<<dim3(4, 128), 256, 0, stream>>>(
      H3h, H3l, W4h, W4l, b4p, nullptr, nullptr, Pp);

  synth<<<4096, 256, 0, stream>>>(Pp, out);
}